// Round 5
// baseline (4706.576 us; speedup 1.0000x reference)
//
#include <hip/hip_runtime.h>
#include <math.h>

// Problem constants: S=1024, B=64, I=512, H=512, 2 layers, fp32.
#define SEQ 1024
#define BATCH 64
#define HID 512
#define MROWS (SEQ * BATCH)   // 65536

// Recurrence decomposition
#define SLICES 8              // j-slices per batch group
#define JW 64                 // output columns per block
#define NGROUPS 32            // batch pairs
#define PSTRIDE ((size_t)NGROUPS * SLICES * 2 * JW)   // 32768 u64 slots per parity

typedef unsigned long long u64;
typedef unsigned int u32;
typedef float f32x2 __attribute__((ext_vector_type(2)));

// ---------------------------------------------------------------------------
// Transpose W_hh (H,H) row-major (j,k) -> Wt[k*H + j].
// ---------------------------------------------------------------------------
__launch_bounds__(256)
__global__ void transposeW(const float* __restrict__ W, float* __restrict__ Wt) {
    __shared__ float tile[32][33];
    int bx = blockIdx.x % 16;           // col-tile
    int by = blockIdx.x / 16;           // row-tile
    int tx = threadIdx.x % 32;
    int ty = threadIdx.x / 32;          // 0..7
    #pragma unroll
    for (int i = 0; i < 32; i += 8)
        tile[ty + i][tx] = W[(size_t)(by * 32 + ty + i) * HID + bx * 32 + tx];
    __syncthreads();
    #pragma unroll
    for (int i = 0; i < 32; i += 8)
        Wt[(size_t)(bx * 32 + ty + i) * HID + by * 32 + tx] = tile[tx][ty + i];
}

// ---------------------------------------------------------------------------
// C[i,j] = sum_k A[i,k] * W[j,k] + b1[j] + b2[j]
// Tiled fp32 GEMM: 64x64 tile per 256-thread block, BK=16, 4x4 micro-tile.
// ---------------------------------------------------------------------------
#define BM 64
#define BN 64
#define BK 16
__launch_bounds__(256)
__global__ void gemm_bias(const float* __restrict__ A, const float* __restrict__ W,
                          const float* __restrict__ b1, const float* __restrict__ b2,
                          float* __restrict__ C) {
    __shared__ float As[BK][BM + 4];
    __shared__ float Ws[BK][BN + 4];

    const int bj = blockIdx.x % (HID / BN);   // 0..7
    const int bi = blockIdx.x / (HID / BN);   // 0..1023
    const int tid = threadIdx.x;
    const int tx = tid % 16;
    const int ty = tid / 16;
    const int row0 = bi * BM;
    const int col0 = bj * BN;

    const int lr = tid / 4;              // 0..63  (tile row)
    const int lk = (tid % 4) * 4;        // 0,4,8,12 (k offset)

    float acc[4][4] = {};

    for (int k0 = 0; k0 < HID; k0 += BK) {
        float4 av = *(const float4*)(A + (size_t)(row0 + lr) * HID + k0 + lk);
        float4 wv = *(const float4*)(W + (size_t)(col0 + lr) * HID + k0 + lk);
        As[lk + 0][lr] = av.x; As[lk + 1][lr] = av.y;
        As[lk + 2][lr] = av.z; As[lk + 3][lr] = av.w;
        Ws[lk + 0][lr] = wv.x; Ws[lk + 1][lr] = wv.y;
        Ws[lk + 2][lr] = wv.z; Ws[lk + 3][lr] = wv.w;
        __syncthreads();
        #pragma unroll
        for (int k = 0; k < BK; ++k) {
            float4 a = *(const float4*)&As[k][ty * 4];
            float4 w = *(const float4*)&Ws[k][tx * 4];
            acc[0][0] += a.x * w.x; acc[0][1] += a.x * w.y; acc[0][2] += a.x * w.z; acc[0][3] += a.x * w.w;
            acc[1][0] += a.y * w.x; acc[1][1] += a.y * w.y; acc[1][2] += a.y * w.z; acc[1][3] += a.y * w.w;
            acc[2][0] += a.z * w.x; acc[2][1] += a.z * w.y; acc[2][2] += a.z * w.z; acc[2][3] += a.z * w.w;
            acc[3][0] += a.w * w.x; acc[3][1] += a.w * w.y; acc[3][2] += a.w * w.z; acc[3][3] += a.w * w.w;
        }
        __syncthreads();
    }

    #pragma unroll
    for (int c = 0; c < 4; ++c) {
        int col = col0 + tx * 4 + c;
        float bias = b1[col] + b2[col];
        #pragma unroll
        for (int r = 0; r < 4; ++r) {
            C[(size_t)(row0 + ty * 4 + r) * HID + col] = acc[r][c] + bias;
        }
    }
}

// ---------------------------------------------------------------------------
// Distributed recurrence, barrier-free steady state.
// Grid 256 = 32 groups x 8 slices, 1024 threads = 16 waves.
// Per step, per wave: pk-FMA its 32-k chunk against register-resident W ->
// write f32x2 partial to parity-double-buffered red -> release-add an LDS
// counter -> immediately poll the 64 h_{t+1} values it owns (tagged agent-
// scope packets, consumer-side tanh) -> write wave-private scratch. Only the
// 2 producer waves spin (acquire) on the counter, reduce red, and publish
// pre-tanh packets. NO __syncthreads in the loop: no vmcnt(0) drains; U
// stores / u_pref prefetches / publishes retire under compute.
// Overwrite safety (slots, parity p reused every 2 steps): publishing tag
// t+1 requires this block to have consumed tag t, which requires ALL group
// producers to have published t, which requires each block's cnt >= 16t,
// i.e. every wave passed its step-(t-1) red-write, which in program order
// follows its poll of tag t-1. Hence no poller of tag t-1 remains when the
// slot is overwritten. Same induction protects red[2].
// ---------------------------------------------------------------------------
__launch_bounds__(1024, 4)
__global__ void rnn_rec6(float* __restrict__ U,            // (S,B,H) in/out
                         const float* __restrict__ Wt,     // (H,H): Wt[k*H+j]
                         const float* __restrict__ h0,     // (B,H)
                         float* __restrict__ hT,           // (B,H)
                         u64* __restrict__ hb)             // slots, zeroed per launch
{
    __shared__ __align__(16) float scratch[16][64];  // per-wave h chunk
    __shared__ __align__(16) f32x2 red[2][16][64];   // 16 KB parity-dbuf partials
    __shared__ u32 cnt;                              // monotonic step counter

    const int blk = blockIdx.x;
    const int s = blk >> 5;              // slice 0..7
    const int g = blk & 31;              // group 0..31
    const int j0 = s * JW;
    const int b0 = g * 2;
    const int tid = threadIdx.x;
    const int jl = tid & 63;             // lane
    const int kq = tid >> 6;             // wave = k-chunk of 32

    // ---- W slice into registers: thread (kq,jl) owns Wt[32kq+kk][j0+jl] ----
    float wreg[32];
    #pragma unroll
    for (int kk = 0; kk < 32; ++kk)
        wreg[kk] = Wt[(size_t)(kq * 32 + kk) * HID + j0 + jl];   // coalesced

    // ---- gather identity: lane owns h-value (gk, gb) ----
    const int gk = kq * 32 + (jl >> 1);
    const int gb = jl & 1;
    const size_t gslot = (((size_t)g * SLICES + (gk >> 6)) * 2 + gb) * JW + (gk & 63);

    // ---- init ----
    scratch[kq][jl] = h0[(size_t)(b0 + gb) * HID + gk];
    if (tid == 0) cnt = 0;

    // ---- producer identity (tid < 128 = waves 0,1) ----
    const int rb = (tid >> 6) & 1;
    const int rj = tid & 63;
    float u_pref = 0.f;
    if (tid < 128)
        u_pref = U[((size_t)0 * BATCH + (b0 + rb)) * HID + j0 + rj];
    __syncthreads();   // one-time: scratch + cnt init visible

    for (int t = 0; t < SEQ; ++t) {
        const int wp = t & 1;                    // red parity
        const int p  = (t + 1) & 1;              // slot parity
        const u32 tag = (u32)(t + 1);

        // ---- phase 1: packed partial dot (W in regs, h in wave scratch) ----
        f32x2 acc = {0.f, 0.f};
        const float4* h4p = (const float4*)scratch[kq];
        #pragma unroll
        for (int q = 0; q < 16; ++q) {
            float4 h4 = h4p[q];                  // (b0,b1) for 2 consecutive k
            f32x2 hA = {h4.x, h4.y};
            f32x2 hB = {h4.z, h4.w};
            f32x2 wA = {wreg[2 * q],     wreg[2 * q]};
            f32x2 wB = {wreg[2 * q + 1], wreg[2 * q + 1]};
            acc = __builtin_elementwise_fma(wA, hA, acc);
            acc = __builtin_elementwise_fma(wB, hB, acc);
        }
        red[wp][kq][jl] = acc;
        if (jl == 0)   // release: orders the red write before the increment
            __hip_atomic_fetch_add(&cnt, 1u, __ATOMIC_RELEASE,
                                   __HIP_MEMORY_SCOPE_WORKGROUP);

        // ---- phase 2 (producer waves only): reduce + publish pre-tanh ----
        if (tid < 128) {
            const u32 target = 16u * (u32)(t + 1);
            int gu = 0;
            while (__hip_atomic_load(&cnt, __ATOMIC_ACQUIRE,
                                     __HIP_MEMORY_SCOPE_WORKGROUP) < target) {
                if (++gu > (1 << 16)) break;     // fail loudly, never hang
            }
            float sum = 0.f;
            const float* rp = (const float*)red[wp];
            #pragma unroll
            for (int q = 0; q < 16; ++q)
                sum += rp[(q * 64 + rj) * 2 + rb];
            float pre = u_pref + sum;
            u64 pkt = ((u64)__float_as_uint(pre) << 32) | tag;
            __hip_atomic_store(hb + p * PSTRIDE
                                  + (((size_t)g * SLICES + s) * 2 + rb) * JW + rj,
                               pkt, __ATOMIC_RELAXED, __HIP_MEMORY_SCOPE_AGENT);
            float v = tanhf(pre);
            U[((size_t)t * BATCH + (b0 + rb)) * HID + j0 + rj] = v;  // y output
            const int tn = (t + 1 < SEQ) ? (t + 1) : t;
            u_pref = U[((size_t)tn * BATCH + (b0 + rb)) * HID + j0 + rj];  // prefetch
        }

        // ---- phase 3: all waves poll their h_{t+1} chunk autonomously ----
        if (t + 1 < SEQ) {
            const u64* slot = hb + p * PSTRIDE + gslot;
            u64 pkt;
            int it = 0;
            do {
                pkt = __hip_atomic_load(slot, __ATOMIC_RELAXED,
                                        __HIP_MEMORY_SCOPE_AGENT);
            } while ((u32)pkt != tag && ++it < (1 << 13));   // bounded
            scratch[kq][jl] = tanhf(__uint_as_float((u32)(pkt >> 32)));
        }
    }

    // ---- tail: s==0 blocks assemble h_SEQ for hT ----
    if (s == 0) {
        const int k = tid >> 1, b = tid & 1;     // 1024 threads <-> 512k x 2b
        const u32 tag = (u32)SEQ;
        const int p = SEQ & 1;
        const u64* slot = hb + p * PSTRIDE
                             + (((size_t)g * SLICES + (k >> 6)) * 2 + b) * JW + (k & 63);
        u64 pkt;
        int it = 0;
        do {
            pkt = __hip_atomic_load(slot, __ATOMIC_RELAXED, __HIP_MEMORY_SCOPE_AGENT);
        } while ((u32)pkt != tag && ++it < (1 << 13));
        hT[(size_t)(b0 + b) * HID + k] = tanhf(__uint_as_float((u32)(pkt >> 32)));
    }
}

// ---------------------------------------------------------------------------
// Launch
// ---------------------------------------------------------------------------
extern "C" void kernel_launch(void* const* d_in, const int* in_sizes, int n_in,
                              void* d_out, int out_size, void* d_ws, size_t ws_size,
                              hipStream_t stream) {
    (void)in_sizes; (void)n_in; (void)out_size; (void)ws_size;

    const float* x      = (const float*)d_in[0];   // (S,B,I)
    const float* hx     = (const float*)d_in[1];   // (2,B,H)
    const float* W_ih0  = (const float*)d_in[2];   // (H,I)
    const float* W_hh0  = (const float*)d_in[3];   // (H,H)
    const float* b_ih0  = (const float*)d_in[4];   // (H,)
    const float* b_hh0  = (const float*)d_in[5];   // (H,)
    const float* W_ih1  = (const float*)d_in[6];   // (H,H)
    const float* W_hh1  = (const float*)d_in[7];   // (H,H)
    const float* b_ih1  = (const float*)d_in[8];   // (H,)
    const float* b_hh1  = (const float*)d_in[9];   // (H,)

    float* out = (float*)d_out;
    float* y1   = out;                                  // (S,B,H)
    float* hT0  = out + (size_t)SEQ * BATCH * HID;      // (B,H)
    float* hT1  = hT0 + (size_t)BATCH * HID;            // (B,H)

    const size_t HB_ELTS = 2 * PSTRIDE;                 // 65536 u64 = 512 KB/layer

    // Workspace: Wt0 (1MB) | Wt1 (1MB) | hb0 (512K) | hb1 (512K) | U0 (128MB)
    float* Wt0 = (float*)d_ws;
    float* Wt1 = Wt0 + (size_t)HID * HID;
    u64* hb0 = (u64*)(Wt1 + (size_t)HID * HID);
    u64* hb1 = hb0 + HB_ELTS;
    float* U0 = (float*)(hb1 + HB_ELTS);

    // zero both slot regions every launch (tag 0 never matches; agent-scope
    // stores write through, so no stale dirty lines survive across runs)
    hipMemsetAsync(hb0, 0, 2 * HB_ELTS * sizeof(u64), stream);

    // 1. transpose W_hh for both layers
    transposeW<<<256, 256, 0, stream>>>(W_hh0, Wt0);
    transposeW<<<256, 256, 0, stream>>>(W_hh1, Wt1);

    // 2. Layer 0 input GEMM: U0 = x @ W_ih0^T + b_ih0 + b_hh0
    gemm_bias<<<(MROWS / BM) * (HID / BN), 256, 0, stream>>>(x, W_ih0, b_ih0, b_hh0, U0);

    // 3. Layer 0 recurrence
    rnn_rec6<<<NGROUPS * SLICES, 1024, 0, stream>>>(U0, Wt0, hx, hT0, hb0);

    // 4. Layer 1 input GEMM: y1 = y0 @ W_ih1^T + b_ih1 + b_hh1
    gemm_bias<<<(MROWS / BM) * (HID / BN), 256, 0, stream>>>(U0, W_ih1, b_ih1, b_hh1, y1);

    // 5. Layer 1 recurrence
    rnn_rec6<<<NGROUPS * SLICES, 1024, 0, stream>>>(y1, Wt1, hx + (size_t)BATCH * HID, hT1, hb1);
}